// Round 3
// baseline (509.154 us; speedup 1.0000x reference)
//
#include <hip/hip_runtime.h>

#define HH 192
#define WW 192
#define LL (HH * WW)   // 36864
#define CC 512
#define KK 64
#define EPSF 1e-12f
typedef unsigned long long ull;

// ---------------------------------------------------------------- k0: wT[c][k] = conv_w[k][c]
__global__ __launch_bounds__(256) void k0_transpose(const float* __restrict__ w,
                                                    float* __restrict__ wT) {
    int idx = blockIdx.x * 256 + threadIdx.x;   // 32768 = KK*CC
    int k = idx >> 9;
    int c = idx & 511;
    wT[c * KK + k] = w[idx];
}

// ---------------------------------------------------------------- k1: lane=pixel, wave=k-group-16
// x streamed as coalesced vector loads; w rides SGPRs (s_load_dwordx16).
// No LDS / barriers in the main loop.
__global__ __launch_bounds__(256) void k1_logits(const float* __restrict__ x,
                                                 const float* __restrict__ wT,
                                                 float* __restrict__ soft,
                                                 float* __restrict__ invn,
                                                 ull* __restrict__ keep) {
    __shared__ float sm1[4][64], sm2[4][64], ssum[4][64], sinv[64];
    __shared__ int   si1[4][64], si2[4][64];
    int t = threadIdx.x, lane = t & 63, wid = t >> 6;
    int l0 = blockIdx.x * 64;
    int kg = __builtin_amdgcn_readfirstlane(wid * 16);

    float acc[16];
#pragma unroll
    for (int q = 0; q < 16; ++q) acc[q] = 0.f;
    float ss = 0.f;

#pragma unroll 4
    for (int c = 0; c < CC; ++c) {
        const float* __restrict__ xrow = x + (size_t)c * LL + l0;   // uniform base
        const float* __restrict__ wr   = wT + (size_t)c * KK + kg;  // uniform -> s_load
        float xv = xrow[lane];                                      // coalesced 256B
        if (wid == 0) ss = fmaf(xv, xv, ss);
#pragma unroll
        for (int q = 0; q < 16; ++q) acc[q] = fmaf(wr[q], xv, acc[q]);
    }

    if (wid == 0) {
        float nn = fmaxf(sqrtf(ss), EPSF);
        float iv = 1.0f / nn;
        sinv[lane] = iv;
        invn[l0 + lane] = iv;
    }
    __syncthreads();
    float iv = sinv[lane];

    // local top-2 over this wave's 16 k (ascending k, strict > keeps lowest index on ties)
    float m1 = -3.0e38f, m2 = -3.0e38f; int i1 = 0, i2 = 0;
#pragma unroll
    for (int q = 0; q < 16; ++q) {
        float lg = acc[q] * iv;
        acc[q] = lg;
        if (lg > m1)      { m2 = m1; i2 = i1; m1 = lg; i1 = kg + q; }
        else if (lg > m2) { m2 = lg; i2 = kg + q; }
    }
    sm1[wid][lane] = m1; si1[wid][lane] = i1;
    sm2[wid][lane] = m2; si2[wid][lane] = i2;
    __syncthreads();

    // merge the 4 waves' top-2 (identical result in every wave)
    float M1 = -3.0e38f, M2 = -3.0e38f; int I1 = 0, I2 = 0;
#pragma unroll
    for (int w2 = 0; w2 < 4; ++w2) {
        float a1 = sm1[w2][lane]; int b1 = si1[w2][lane];
        float a2 = sm2[w2][lane]; int b2 = si2[w2][lane];
        if (a1 > M1 || (a1 == M1 && b1 < I1)) { M2 = M1; I2 = I1; M1 = a1; I1 = b1; }
        else if (a1 > M2 || (a1 == M2 && b1 < I2)) { M2 = a1; I2 = b1; }
        if (a2 > M1 || (a2 == M1 && b2 < I1)) { M2 = M1; I2 = I1; M1 = a2; I1 = b2; }
        else if (a2 > M2 || (a2 == M2 && b2 < I2)) { M2 = a2; I2 = b2; }
    }

    float es = 0.f;
#pragma unroll
    for (int q = 0; q < 16; ++q) { float e = __expf(acc[q] - M1); acc[q] = e; es += e; }
    ssum[wid][lane] = es;
    __syncthreads();
    float St = ssum[0][lane] + ssum[1][lane] + ssum[2][lane] + ssum[3][lane];
    float rs = 1.0f / St;

    float4* sp = (float4*)(soft + (size_t)(l0 + lane) * KK + kg);
#pragma unroll
    for (int q4 = 0; q4 < 4; ++q4) {
        float4 v; v.x = acc[q4*4+0]*rs; v.y = acc[q4*4+1]*rs;
                  v.z = acc[q4*4+2]*rs; v.w = acc[q4*4+3]*rs;
        sp[q4] = v;
    }
    if (wid == 0) keep[l0 + lane] = (1ull << I1) | (1ull << I2);
}

// ---------------------------------------------------------------- k2: w2[l][k] = soft*cnt*border^4*invn[l] (in place), S[k] += unscaled
__global__ __launch_bounds__(256) void k2_weight(float* __restrict__ soft,
                                                 const ull* __restrict__ keep,
                                                 const float* __restrict__ invn,
                                                 float* __restrict__ S) {
    int t = threadIdx.x, lane = t & 63, wid = t >> 6;
    int l0 = blockIdx.x * 64 + wid * 16;
    float sk = 0.f;
#pragma unroll 4
    for (int p = 0; p < 16; ++p) {
        int l = l0 + p;                           // wave-uniform
        int i = l / WW, j = l % WW;
        int m = min(min(i, HH - 1 - i), min(j, WW - 1 - j));
        float bm = (float)m; bm *= bm; bm *= bm;  // m^4
        int cnt = 0;
#pragma unroll
        for (int di = -1; di <= 1; ++di) {
            int ii = i + di;
            if (ii < 0 || ii >= HH) continue;
#pragma unroll
            for (int dj = -1; dj <= 1; ++dj) {
                int jj = j + dj;
                if (jj < 0 || jj >= WW) continue;
                ull nb = keep[ii * WW + jj];      // uniform -> s_load
                cnt += (int)((nb >> lane) & 1ull);
            }
        }
        float v = soft[(size_t)l * KK + lane];    // coalesced 256B
        float u = v * (float)cnt * bm;            // unscaled weight
        sk += u;
        soft[(size_t)l * KK + lane] = u * invn[l];
    }
    atomicAdd(&S[lane], sk);
}

// ---------------------------------------------------------------- k3: accg[k][c] += sum_l w2[l][k] * x[c][l]
// block 128 thr, tile 64k x 128c, chunk 128 l; 8k x 8c per thread
#define K3_NCHUNK 288
#define K3_CHUNK (LL / K3_NCHUNK)   // 128
#define K3_LT 32

__global__ __launch_bounds__(128) void k3_gemm(const float* __restrict__ w2,
                                               const float* __restrict__ x,
                                               float* __restrict__ accg) {
    __shared__ float xt[K3_LT][132];   // [lt][c], pad 132 keeps b128 aligned
    __shared__ float wt[K3_LT][64];    // [lt][k]
    int chunk = blockIdx.x;            // 0..287
    int ctile = blockIdx.y;            // 0..3
    int l0 = chunk * K3_CHUNK;
    int c0 = ctile * 128;
    int t = threadIdx.x;
    int tx = t & 15, ty = (t >> 4) & 7;

    float acc[8][8];
#pragma unroll
    for (int r = 0; r < 8; ++r)
#pragma unroll
        for (int s = 0; s < 8; ++s) acc[r][s] = 0.f;

    for (int lb = 0; lb < K3_CHUNK; lb += K3_LT) {
        // stage x transpose: xt[lt][c] = x[c0+c][l0+lb+lt]  (reads coalesced along l)
        int lt = t & 31, crow = t >> 5;          // crow 0..3
        int gl = l0 + lb + lt;
#pragma unroll
        for (int s = 0; s < 32; ++s)
            xt[lt][crow + 4 * s] = x[(size_t)(c0 + crow + 4 * s) * LL + gl];
        // stage w2: wt[lt][k]
        int kk = t & 63, lrow = t >> 6;          // lrow 0..1
#pragma unroll
        for (int s = 0; s < 16; ++s)
            wt[lrow + 2 * s][kk] = w2[(size_t)(l0 + lb + lrow + 2 * s) * KK + kk];
        __syncthreads();
#pragma unroll 4
        for (int l2 = 0; l2 < K3_LT; ++l2) {
            float4 xa = *(const float4*)&xt[l2][tx * 4];
            float4 xb = *(const float4*)&xt[l2][64 + tx * 4];
            float4 wa = *(const float4*)&wt[l2][ty * 4];
            float4 wb = *(const float4*)&wt[l2][32 + ty * 4];
            float xs[8] = {xa.x, xa.y, xa.z, xa.w, xb.x, xb.y, xb.z, xb.w};
            float wk[8] = {wa.x, wa.y, wa.z, wa.w, wb.x, wb.y, wb.z, wb.w};
#pragma unroll
            for (int r = 0; r < 8; ++r)
#pragma unroll
                for (int s = 0; s < 8; ++s) acc[r][s] = fmaf(wk[r], xs[s], acc[r][s]);
        }
        __syncthreads();
    }
#pragma unroll
    for (int r = 0; r < 8; ++r) {
        int k = (r < 4) ? (ty * 4 + r) : (32 + ty * 4 + r - 4);
#pragma unroll
        for (int s = 0; s < 8; ++s) {
            int c = (s < 4) ? (tx * 4 + s) : (64 + tx * 4 + s - 4);
            atomicAdd(&accg[k * CC + c0 + c], acc[r][s]);
        }
    }
}

// ---------------------------------------------------------------- k4a: centroid subtract + row L2-norm
__global__ __launch_bounds__(256) void k4a_rownorm(const float* __restrict__ accg,
                                                   const float* __restrict__ S,
                                                   const float* __restrict__ cent,
                                                   float* __restrict__ out,
                                                   float* __restrict__ gsum) {
    __shared__ float red[256];
    int k = blockIdx.x;
    int tid = threadIdx.x;
    float Sk = S[k];
    float v0 = accg[k * CC + tid]       - Sk * cent[k * CC + tid];
    float v1 = accg[k * CC + tid + 256] - Sk * cent[k * CC + tid + 256];
    red[tid] = v0 * v0 + v1 * v1; __syncthreads();
    for (int off = 128; off > 0; off >>= 1) {
        if (tid < off) red[tid] += red[tid + off];
        __syncthreads();
    }
    float tot = red[0];
    float rn = 1.0f / fmaxf(sqrtf(tot), EPSF);
    out[k * CC + tid]       = v0 * rn;
    out[k * CC + tid + 256] = v1 * rn;
    if (tid == 0) atomicAdd(gsum, tot * rn * rn);
}

// ---------------------------------------------------------------- k4b: global L2 scale
__global__ __launch_bounds__(256) void k4b_gnorm(float* __restrict__ out,
                                                 const float* __restrict__ gsum) {
    float g = gsum[0];
    float rg = 1.0f / fmaxf(sqrtf(g), EPSF);
    int idx = blockIdx.x * 256 + threadIdx.x;
    out[idx] *= rg;
}

// ----------------------------------------------------------------
extern "C" void kernel_launch(void* const* d_in, const int* in_sizes, int n_in,
                              void* d_out, int out_size, void* d_ws, size_t ws_size,
                              hipStream_t stream) {
    const float* x      = (const float*)d_in[0];   // (512,192,192)
    const float* conv_w = (const float*)d_in[1];   // (64,512)
    const float* cent   = (const float*)d_in[2];   // (64,512)
    float* out = (float*)d_out;                    // 32768 fp32

    float* ws   = (float*)d_ws;
    float* wT   = ws;                               // 32768
    float* soft = ws + 32768;                       // KK*LL (becomes w2 in place)
    float* invn = soft + (size_t)KK * LL;           // LL
    ull*   keep = (ull*)(invn + LL);                // LL u64 (8B aligned)
    float* accg = (float*)(keep + LL);              // KK*CC
    float* S    = accg + (size_t)KK * CC;           // KK
    float* gsum = S + KK;                           // 1

    hipMemsetAsync(accg, 0, ((size_t)KK * CC + KK + 1) * sizeof(float), stream);

    k0_transpose<<<(KK * CC) / 256, 256, 0, stream>>>(conv_w, wT);
    k1_logits<<<LL / 64, 256, 0, stream>>>(x, wT, soft, invn, keep);
    k2_weight<<<LL / 64, 256, 0, stream>>>(soft, keep, invn, S);
    k3_gemm<<<dim3(K3_NCHUNK, CC / 128), 128, 0, stream>>>(soft, x, accg);
    k4a_rownorm<<<KK, 256, 0, stream>>>(accg, S, cent, out, gsum);
    k4b_gnorm<<<(KK * CC) / 256, 256, 0, stream>>>(out, gsum);
}

// Round 4
// 288.342 us; speedup vs baseline: 1.7658x; 1.7658x over previous
//
#include <hip/hip_runtime.h>

#define HH 192
#define WW 192
#define LL (HH * WW)   // 36864
#define CC 512
#define KK 64
#define EPSF 1e-12f
typedef unsigned long long ull;

// k3 decomposition
#define NCHUNK 128
#define CHUNKL (LL / NCHUNK)   // 288
#define LT 32
#define CT 128

// ---------------------------------------------------------------- k0: wT[c][k] = conv_w[k][c]
__global__ __launch_bounds__(256) void k0_transpose(const float* __restrict__ w,
                                                    float* __restrict__ wT) {
    int idx = blockIdx.x * 256 + threadIdx.x;   // 32768 = KK*CC
    int k = idx >> 9;
    int c = idx & 511;
    wT[c * KK + k] = w[idx];
}

// ---------------------------------------------------------------- k1: lane=pixel, wave=k-group-16
__global__ __launch_bounds__(256) void k1_logits(const float* __restrict__ x,
                                                 const float* __restrict__ wT,
                                                 float* __restrict__ soft,
                                                 float* __restrict__ invn,
                                                 ull* __restrict__ keep) {
    __shared__ float sm1[4][64], sm2[4][64], ssum[4][64], sinv[64];
    __shared__ int   si1[4][64], si2[4][64];
    int t = threadIdx.x, lane = t & 63, wid = t >> 6;
    int l0 = blockIdx.x * 64;
    int kg = __builtin_amdgcn_readfirstlane(wid * 16);

    float acc[16];
#pragma unroll
    for (int q = 0; q < 16; ++q) acc[q] = 0.f;
    float ss = 0.f;

#pragma unroll 4
    for (int c = 0; c < CC; ++c) {
        const float* __restrict__ xrow = x + (size_t)c * LL + l0;   // uniform base
        const float* __restrict__ wr   = wT + (size_t)c * KK + kg;  // uniform -> s_load
        float xv = xrow[lane];                                      // coalesced 256B
        if (wid == 0) ss = fmaf(xv, xv, ss);
#pragma unroll
        for (int q = 0; q < 16; ++q) acc[q] = fmaf(wr[q], xv, acc[q]);
    }

    if (wid == 0) {
        float iv = 1.0f / fmaxf(sqrtf(ss), EPSF);
        sinv[lane] = iv;
        invn[l0 + lane] = iv;
    }
    __syncthreads();
    float iv = sinv[lane];

    float m1 = -3.0e38f, m2 = -3.0e38f; int i1 = 0, i2 = 0;
#pragma unroll
    for (int q = 0; q < 16; ++q) {
        float lg = acc[q] * iv;
        acc[q] = lg;
        if (lg > m1)      { m2 = m1; i2 = i1; m1 = lg; i1 = kg + q; }
        else if (lg > m2) { m2 = lg; i2 = kg + q; }
    }
    sm1[wid][lane] = m1; si1[wid][lane] = i1;
    sm2[wid][lane] = m2; si2[wid][lane] = i2;
    __syncthreads();

    float M1 = -3.0e38f, M2 = -3.0e38f; int I1 = 0, I2 = 0;
#pragma unroll
    for (int w2 = 0; w2 < 4; ++w2) {
        float a1 = sm1[w2][lane]; int b1 = si1[w2][lane];
        float a2 = sm2[w2][lane]; int b2 = si2[w2][lane];
        if (a1 > M1 || (a1 == M1 && b1 < I1)) { M2 = M1; I2 = I1; M1 = a1; I1 = b1; }
        else if (a1 > M2 || (a1 == M2 && b1 < I2)) { M2 = a1; I2 = b1; }
        if (a2 > M1 || (a2 == M1 && b2 < I1)) { M2 = M1; I2 = I1; M1 = a2; I1 = b2; }
        else if (a2 > M2 || (a2 == M2 && b2 < I2)) { M2 = a2; I2 = b2; }
    }

    float es = 0.f;
#pragma unroll
    for (int q = 0; q < 16; ++q) { float e = __expf(acc[q] - M1); acc[q] = e; es += e; }
    ssum[wid][lane] = es;
    __syncthreads();
    float St = ssum[0][lane] + ssum[1][lane] + ssum[2][lane] + ssum[3][lane];
    float rs = 1.0f / St;

    float4* sp = (float4*)(soft + (size_t)(l0 + lane) * KK + kg);
#pragma unroll
    for (int q4 = 0; q4 < 4; ++q4) {
        float4 v; v.x = acc[q4*4+0]*rs; v.y = acc[q4*4+1]*rs;
                  v.z = acc[q4*4+2]*rs; v.w = acc[q4*4+3]*rs;
        sp[q4] = v;
    }
    if (wid == 0) keep[l0 + lane] = (1ull << I1) | (1ull << I2);
}

// ---------------------------------------------------------------- k2: w2[l][k] = soft*cnt*border^4*invn[l] (in place), S[k] += unscaled
__global__ __launch_bounds__(256) void k2_weight(float* __restrict__ soft,
                                                 const ull* __restrict__ keep,
                                                 const float* __restrict__ invn,
                                                 float* __restrict__ S) {
    __shared__ float sred[4][64];
    int t = threadIdx.x, lane = t & 63, wid = t >> 6;
    int l0 = blockIdx.x * 64 + wid * 16;
    float sk = 0.f;
#pragma unroll 4
    for (int p = 0; p < 16; ++p) {
        int l = l0 + p;                           // wave-uniform
        int i = l / WW, j = l % WW;
        int m = min(min(i, HH - 1 - i), min(j, WW - 1 - j));
        float bm = (float)m; bm *= bm; bm *= bm;  // m^4
        int cnt = 0;
#pragma unroll
        for (int di = -1; di <= 1; ++di) {
            int ii = i + di;
            if (ii < 0 || ii >= HH) continue;
#pragma unroll
            for (int dj = -1; dj <= 1; ++dj) {
                int jj = j + dj;
                if (jj < 0 || jj >= WW) continue;
                ull nb = keep[ii * WW + jj];      // uniform -> s_load
                cnt += (int)((nb >> lane) & 1ull);
            }
        }
        float v = soft[(size_t)l * KK + lane];    // coalesced 256B
        float u = v * (float)cnt * bm;            // unscaled weight
        sk += u;
        soft[(size_t)l * KK + lane] = u * invn[l];
    }
    sred[wid][lane] = sk;
    __syncthreads();
    if (wid == 0)
        atomicAdd(&S[lane], sred[0][lane] + sred[1][lane] + sred[2][lane] + sred[3][lane]);
}

// ---------------------------------------------------------------- k3: partials[ch][k][c] = sum_{l in chunk} w2[l][k] * xn[c][l]
// 128 thr; tile 64k x 128c; 8k x 8c per thread; no atomics.
__global__ __launch_bounds__(128) void k3_gemm(const float* __restrict__ w2,
                                               const float* __restrict__ x,
                                               float* __restrict__ partials) {
    __shared__ float wt[LT][KK];        // stride 64: row-dir reads conflict-free
    __shared__ float xt[LT][CT + 4];    // stride 132: row-dir reads conflict-free
    int bx = blockIdx.x;
    int chunk = bx >> 2;                // 0..127
    int c0 = (bx & 3) * CT;
    int l0 = chunk * CHUNKL;
    int t = threadIdx.x;
    int tx = t & 15, ty = t >> 4;       // tx->c, ty->k

    float acc[8][8];
#pragma unroll
    for (int r = 0; r < 8; ++r)
#pragma unroll
        for (int s = 0; s < 8; ++s) acc[r][s] = 0.f;

    for (int lb = 0; lb < CHUNKL; lb += LT) {
        // stage w2 tile: [lt][k], global coalesced along k
        {
            int kk = t & 63, r2 = t >> 6;        // r2 0..1
#pragma unroll
            for (int i = 0; i < 16; ++i)
                wt[r2 + 2 * i][kk] = w2[(size_t)(l0 + lb + r2 + 2 * i) * KK + kk];
        }
        // stage x tile: [lt][c], global coalesced along l
        {
            int lt = t & 31, cb = t >> 5;        // cb 0..3
            int gl = l0 + lb + lt;
#pragma unroll
            for (int j = 0; j < 32; ++j)
                xt[lt][cb + 4 * j] = x[(size_t)(c0 + cb + 4 * j) * LL + gl];
        }
        __syncthreads();
#pragma unroll 2
        for (int l2 = 0; l2 < LT; ++l2) {
            float4 wa = *(const float4*)&wt[l2][ty * 4];
            float4 wb = *(const float4*)&wt[l2][32 + ty * 4];
            float4 xa = *(const float4*)&xt[l2][tx * 4];
            float4 xb = *(const float4*)&xt[l2][64 + tx * 4];
            float wk[8] = {wa.x, wa.y, wa.z, wa.w, wb.x, wb.y, wb.z, wb.w};
            float xs[8] = {xa.x, xa.y, xa.z, xa.w, xb.x, xb.y, xb.z, xb.w};
#pragma unroll
            for (int r = 0; r < 8; ++r)
#pragma unroll
                for (int s = 0; s < 8; ++s) acc[r][s] = fmaf(wk[r], xs[s], acc[r][s]);
        }
        __syncthreads();
    }
    float* pp = partials + (size_t)chunk * KK * CC;
#pragma unroll
    for (int r = 0; r < 8; ++r) {
        int k = (r < 4) ? (ty * 4 + r) : (32 + ty * 4 + r - 4);
#pragma unroll
        for (int s = 0; s < 8; ++s) {
            int c = (s < 4) ? (tx * 4 + s) : (64 + tx * 4 + s - 4);
            pp[(size_t)k * CC + c0 + c] = acc[r][s];
        }
    }
}

// ---------------------------------------------------------------- k4a: reduce partials + centroid subtract + row L2-norm
__global__ __launch_bounds__(256) void k4a_rownorm(const float* __restrict__ partials,
                                                   const float* __restrict__ S,
                                                   const float* __restrict__ cent,
                                                   float* __restrict__ out,
                                                   float* __restrict__ gsum) {
    __shared__ float red[256];
    int k = blockIdx.x;
    int tid = threadIdx.x;
    float v0 = 0.f, v1 = 0.f;
    const float* pk = partials + (size_t)k * CC;
    for (int ch = 0; ch < NCHUNK; ++ch) {
        v0 += pk[(size_t)ch * KK * CC + tid];
        v1 += pk[(size_t)ch * KK * CC + tid + 256];
    }
    float Sk = S[k];
    v0 -= Sk * cent[k * CC + tid];
    v1 -= Sk * cent[k * CC + tid + 256];
    red[tid] = v0 * v0 + v1 * v1; __syncthreads();
    for (int off = 128; off > 0; off >>= 1) {
        if (tid < off) red[tid] += red[tid + off];
        __syncthreads();
    }
    float tot = red[0];
    float rn = 1.0f / fmaxf(sqrtf(tot), EPSF);
    out[k * CC + tid]       = v0 * rn;
    out[k * CC + tid + 256] = v1 * rn;
    if (tid == 0) atomicAdd(gsum, tot * rn * rn);
}

// ---------------------------------------------------------------- k4b: global L2 scale
__global__ __launch_bounds__(256) void k4b_gnorm(float* __restrict__ out,
                                                 const float* __restrict__ gsum) {
    float g = gsum[0];
    float rg = 1.0f / fmaxf(sqrtf(g), EPSF);
    int idx = blockIdx.x * 256 + threadIdx.x;
    out[idx] *= rg;
}

// ----------------------------------------------------------------
extern "C" void kernel_launch(void* const* d_in, const int* in_sizes, int n_in,
                              void* d_out, int out_size, void* d_ws, size_t ws_size,
                              hipStream_t stream) {
    const float* x      = (const float*)d_in[0];   // (512,192,192)
    const float* conv_w = (const float*)d_in[1];   // (64,512)
    const float* cent   = (const float*)d_in[2];   // (64,512)
    float* out = (float*)d_out;                    // 32768 fp32

    float* ws   = (float*)d_ws;
    float* wT   = ws;                               // 32768
    float* soft = wT + 32768;                       // KK*LL (becomes w2 in place)
    float* invn = soft + (size_t)KK * LL;           // LL
    float* S    = invn + LL;                        // 64
    float* gsum = S + KK;                           // 1
    // align to 16B for keep (ull) and partials
    size_t off = 32768 + (size_t)KK * LL + LL + KK + 1;
    off = (off + 3) & ~(size_t)3;
    ull*   keep = (ull*)(ws + off);                 // LL u64
    float* partials = ws + off + 2 * (size_t)LL;    // NCHUNK*KK*CC floats (16.8 MB)

    hipMemsetAsync(S, 0, (KK + 1) * sizeof(float), stream);

    k0_transpose<<<(KK * CC) / 256, 256, 0, stream>>>(conv_w, wT);
    k1_logits<<<LL / 64, 256, 0, stream>>>(x, wT, soft, invn, keep);
    k2_weight<<<LL / 64, 256, 0, stream>>>(soft, keep, invn, S);
    k3_gemm<<<NCHUNK * (CC / CT), 128, 0, stream>>>(soft, x, partials);
    k4a_rownorm<<<KK, 256, 0, stream>>>(partials, S, cent, out, gsum);
    k4b_gnorm<<<(KK * CC) / 256, 256, 0, stream>>>(out, gsum);
}

// Round 5
// 243.091 us; speedup vs baseline: 2.0945x; 1.1862x over previous
//
#include <hip/hip_runtime.h>

#define HH 192
#define WW 192
#define LL (HH * WW)   // 36864
#define CC 512
#define KK 64
#define EPSF 1e-12f
typedef unsigned long long ull;

// k3 decomposition
#define NCHUNK 128
#define CHUNKL (LL / NCHUNK)   // 288
#define LT 32
#define CT 128

// ---------------------------------------------------------------- k0: wT[c][k] = conv_w[k][c]
__global__ __launch_bounds__(256) void k0_transpose(const float* __restrict__ w,
                                                    float* __restrict__ wT) {
    int idx = blockIdx.x * 256 + threadIdx.x;   // 32768 = KK*CC
    int k = idx >> 9;
    int c = idx & 511;
    wT[c * KK + k] = w[idx];
}

// ---------------------------------------------------------------- k1: lane=pixel, wave=k-group-16, 16-deep x pipeline
__global__ __launch_bounds__(256) void k1_logits(const float* __restrict__ x,
                                                 const float* __restrict__ wT,
                                                 float* __restrict__ soft,
                                                 float* __restrict__ invn,
                                                 ull* __restrict__ keep) {
    __shared__ float sm1[4][64], sm2[4][64], ssum[4][64], sinv[64];
    __shared__ int   si1[4][64], si2[4][64];
    int t = threadIdx.x, lane = t & 63, wid = t >> 6;
    int l0 = blockIdx.x * 64;
    int kg = __builtin_amdgcn_readfirstlane(wid * 16);

    const float* __restrict__ xcol = x + l0 + lane;   // advance by c*LL

    float acc[16];
#pragma unroll
    for (int q = 0; q < 16; ++q) acc[q] = 0.f;
    float ss = 0.f;

    float xp[16], xn[16];
#pragma unroll
    for (int q = 0; q < 16; ++q) xp[q] = xcol[(size_t)q * LL];

    for (int cb = 0; cb < CC; cb += 16) {
        // prefetch next batch (uniform branch; last iter skips)
        if (cb + 16 < CC) {
#pragma unroll
            for (int q = 0; q < 16; ++q) xn[q] = xcol[(size_t)(cb + 16 + q) * LL];
        }
#pragma unroll
        for (int cc = 0; cc < 16; ++cc) {
            float xv = xp[cc];
            ss = fmaf(xv, xv, ss);                            // redundant in waves 1-3; branch-free
            const float* wr = wT + (size_t)(cb + cc) * KK + kg;  // uniform -> s_load
#pragma unroll
            for (int q = 0; q < 16; ++q) acc[q] = fmaf(wr[q], xv, acc[q]);
        }
        if (cb + 16 < CC) {
#pragma unroll
            for (int q = 0; q < 16; ++q) xp[q] = xn[q];
        }
    }

    if (wid == 0) {
        float iv = 1.0f / fmaxf(sqrtf(ss), EPSF);
        sinv[lane] = iv;
        invn[l0 + lane] = iv;
    }
    __syncthreads();
    float iv = sinv[lane];

    float m1 = -3.0e38f, m2 = -3.0e38f; int i1 = 0, i2 = 0;
#pragma unroll
    for (int q = 0; q < 16; ++q) {
        float lg = acc[q] * iv;
        acc[q] = lg;
        if (lg > m1)      { m2 = m1; i2 = i1; m1 = lg; i1 = kg + q; }
        else if (lg > m2) { m2 = lg; i2 = kg + q; }
    }
    sm1[wid][lane] = m1; si1[wid][lane] = i1;
    sm2[wid][lane] = m2; si2[wid][lane] = i2;
    __syncthreads();

    float M1 = -3.0e38f, M2 = -3.0e38f; int I1 = 0, I2 = 0;
#pragma unroll
    for (int w2 = 0; w2 < 4; ++w2) {
        float a1 = sm1[w2][lane]; int b1 = si1[w2][lane];
        float a2 = sm2[w2][lane]; int b2 = si2[w2][lane];
        if (a1 > M1 || (a1 == M1 && b1 < I1)) { M2 = M1; I2 = I1; M1 = a1; I1 = b1; }
        else if (a1 > M2 || (a1 == M2 && b1 < I2)) { M2 = a1; I2 = b1; }
        if (a2 > M1 || (a2 == M1 && b2 < I1)) { M2 = M1; I2 = I1; M1 = a2; I1 = b2; }
        else if (a2 > M2 || (a2 == M2 && b2 < I2)) { M2 = a2; I2 = b2; }
    }

    float es = 0.f;
#pragma unroll
    for (int q = 0; q < 16; ++q) { float e = __expf(acc[q] - M1); acc[q] = e; es += e; }
    ssum[wid][lane] = es;
    __syncthreads();
    float St = ssum[0][lane] + ssum[1][lane] + ssum[2][lane] + ssum[3][lane];
    float rs = 1.0f / St;

    float4* sp = (float4*)(soft + (size_t)(l0 + lane) * KK + kg);
#pragma unroll
    for (int q4 = 0; q4 < 4; ++q4) {
        float4 v; v.x = acc[q4*4+0]*rs; v.y = acc[q4*4+1]*rs;
                  v.z = acc[q4*4+2]*rs; v.w = acc[q4*4+3]*rs;
        sp[q4] = v;
    }
    if (wid == 0) keep[l0 + lane] = (1ull << I1) | (1ull << I2);
}

// ---------------------------------------------------------------- k2: w2[l][k] = soft*cnt*border^4*invn[l] (in place), S[k] += unscaled
__global__ __launch_bounds__(256) void k2_weight(float* __restrict__ soft,
                                                 const ull* __restrict__ keep,
                                                 const float* __restrict__ invn,
                                                 float* __restrict__ S) {
    __shared__ float sred[4][64];
    int t = threadIdx.x, lane = t & 63, wid = t >> 6;
    int l0 = blockIdx.x * 64 + wid * 16;
    float sk = 0.f;
#pragma unroll 4
    for (int p = 0; p < 16; ++p) {
        int l = l0 + p;                           // wave-uniform
        int i = l / WW, j = l % WW;
        int m = min(min(i, HH - 1 - i), min(j, WW - 1 - j));
        float bm = (float)m; bm *= bm; bm *= bm;  // m^4
        int cnt = 0;
#pragma unroll
        for (int di = -1; di <= 1; ++di) {
            int ii = i + di;
            if (ii < 0 || ii >= HH) continue;
#pragma unroll
            for (int dj = -1; dj <= 1; ++dj) {
                int jj = j + dj;
                if (jj < 0 || jj >= WW) continue;
                ull nb = keep[ii * WW + jj];      // uniform -> s_load
                cnt += (int)((nb >> lane) & 1ull);
            }
        }
        float v = soft[(size_t)l * KK + lane];    // coalesced 256B
        float u = v * (float)cnt * bm;            // unscaled weight
        sk += u;
        soft[(size_t)l * KK + lane] = u * invn[l];
    }
    sred[wid][lane] = sk;
    __syncthreads();
    if (wid == 0)
        atomicAdd(&S[lane], sred[0][lane] + sred[1][lane] + sred[2][lane] + sred[3][lane]);
}

// ---------------------------------------------------------------- k3: partials[ch][k][c] = sum_{l in chunk} w2[l][k] * xn[c][l]
// 256 thr; tile 64k x 128c; 4k x 8c per thread; no atomics; float4 stores.
__global__ __launch_bounds__(256) void k3_gemm(const float* __restrict__ w2,
                                               const float* __restrict__ x,
                                               float* __restrict__ partials) {
    __shared__ float wt[LT][KK];        // row-dir reads conflict-free
    __shared__ float xt[LT][CT + 4];    // stride 132 keeps b128 16B-aligned
    int bx = blockIdx.x;
    int chunk = bx >> 2;                // 0..127
    int c0 = (bx & 3) * CT;
    int l0 = chunk * CHUNKL;
    int t = threadIdx.x;
    int tx = t & 15, ty = t >> 4;       // tx->c (8), ty->k (4)

    float acc[4][8];
#pragma unroll
    for (int r = 0; r < 4; ++r)
#pragma unroll
        for (int s = 0; s < 8; ++s) acc[r][s] = 0.f;

    for (int lb = 0; lb < CHUNKL; lb += LT) {
        // stage w2 tile: [lt][k], global coalesced along k
        {
            int kk = t & 63, r2 = t >> 6;        // r2 0..3
#pragma unroll
            for (int i = 0; i < 8; ++i)
                wt[r2 + 4 * i][kk] = w2[(size_t)(l0 + lb + r2 + 4 * i) * KK + kk];
        }
        // stage x tile: [lt][c], global coalesced along l
        {
            int lt = t & 31, cb = t >> 5;        // cb 0..7
            int gl = l0 + lb + lt;
#pragma unroll
            for (int j = 0; j < 16; ++j)
                xt[lt][cb + 8 * j] = x[(size_t)(c0 + cb + 8 * j) * LL + gl];
        }
        __syncthreads();
#pragma unroll 2
        for (int l2 = 0; l2 < LT; ++l2) {
            float4 wa = *(const float4*)&wt[l2][ty * 4];
            float4 xa = *(const float4*)&xt[l2][tx * 4];
            float4 xb = *(const float4*)&xt[l2][64 + tx * 4];
            float wk[4] = {wa.x, wa.y, wa.z, wa.w};
            float xs[8] = {xa.x, xa.y, xa.z, xa.w, xb.x, xb.y, xb.z, xb.w};
#pragma unroll
            for (int r = 0; r < 4; ++r)
#pragma unroll
                for (int s = 0; s < 8; ++s) acc[r][s] = fmaf(wk[r], xs[s], acc[r][s]);
        }
        __syncthreads();
    }
    float* pp = partials + (size_t)chunk * KK * CC;
#pragma unroll
    for (int r = 0; r < 4; ++r) {
        int k = ty * 4 + r;
        float4 va; va.x = acc[r][0]; va.y = acc[r][1]; va.z = acc[r][2]; va.w = acc[r][3];
        float4 vb; vb.x = acc[r][4]; vb.y = acc[r][5]; vb.z = acc[r][6]; vb.w = acc[r][7];
        *(float4*)&pp[(size_t)k * CC + c0 + tx * 4]      = va;
        *(float4*)&pp[(size_t)k * CC + c0 + 64 + tx * 4] = vb;
    }
}

// ---------------------------------------------------------------- k4a: reduce partials + centroid subtract + row L2-norm (512 thr)
__global__ __launch_bounds__(512) void k4a_rownorm(const float* __restrict__ partials,
                                                   const float* __restrict__ S,
                                                   const float* __restrict__ cent,
                                                   float* __restrict__ out,
                                                   float* __restrict__ gsum) {
    __shared__ float red[512];
    int k = blockIdx.x;
    int tid = threadIdx.x;          // = c
    const float* pk = partials + (size_t)k * CC + tid;
    float s0 = 0.f, s1 = 0.f, s2 = 0.f, s3 = 0.f;
    for (int ch = 0; ch < NCHUNK; ch += 4) {
        s0 += pk[(size_t)(ch + 0) * KK * CC];
        s1 += pk[(size_t)(ch + 1) * KK * CC];
        s2 += pk[(size_t)(ch + 2) * KK * CC];
        s3 += pk[(size_t)(ch + 3) * KK * CC];
    }
    float v = (s0 + s1) + (s2 + s3);
    v -= S[k] * cent[k * CC + tid];
    red[tid] = v * v; __syncthreads();
    for (int off = 256; off > 0; off >>= 1) {
        if (tid < off) red[tid] += red[tid + off];
        __syncthreads();
    }
    float tot = red[0];
    float rn = 1.0f / fmaxf(sqrtf(tot), EPSF);
    out[k * CC + tid] = v * rn;
    if (tid == 0) atomicAdd(gsum, tot * rn * rn);
}

// ---------------------------------------------------------------- k4b: global L2 scale
__global__ __launch_bounds__(256) void k4b_gnorm(float* __restrict__ out,
                                                 const float* __restrict__ gsum) {
    float g = gsum[0];
    float rg = 1.0f / fmaxf(sqrtf(g), EPSF);
    int idx = blockIdx.x * 256 + threadIdx.x;
    out[idx] *= rg;
}

// ----------------------------------------------------------------
extern "C" void kernel_launch(void* const* d_in, const int* in_sizes, int n_in,
                              void* d_out, int out_size, void* d_ws, size_t ws_size,
                              hipStream_t stream) {
    const float* x      = (const float*)d_in[0];   // (512,192,192)
    const float* conv_w = (const float*)d_in[1];   // (64,512)
    const float* cent   = (const float*)d_in[2];   // (64,512)
    float* out = (float*)d_out;                    // 32768 fp32

    float* ws   = (float*)d_ws;
    float* wT   = ws;                               // 32768
    float* soft = wT + 32768;                       // KK*LL (becomes w2 in place)
    float* invn = soft + (size_t)KK * LL;           // LL
    float* S    = invn + LL;                        // 64
    float* gsum = S + KK;                           // 1
    size_t off = 32768 + (size_t)KK * LL + LL + KK + 1;
    off = (off + 3) & ~(size_t)3;                   // 16B align for ull
    ull*   keep = (ull*)(ws + off);                 // LL u64
    float* partials = ws + off + 2 * (size_t)LL;    // NCHUNK*KK*CC floats (16.8 MB)

    hipMemsetAsync(S, 0, (KK + 1) * sizeof(float), stream);

    k0_transpose<<<(KK * CC) / 256, 256, 0, stream>>>(conv_w, wT);
    k1_logits<<<LL / 64, 256, 0, stream>>>(x, wT, soft, invn, keep);
    k2_weight<<<LL / 64, 256, 0, stream>>>(soft, keep, invn, S);
    k3_gemm<<<NCHUNK * (CC / CT), 256, 0, stream>>>(soft, x, partials);
    k4a_rownorm<<<KK, 512, 0, stream>>>(partials, S, cent, out, gsum);
    k4b_gnorm<<<(KK * CC) / 256, 256, 0, stream>>>(out, gsum);
}